// Round 5
// baseline (149.854 us; speedup 1.0000x reference)
//
#include <hip/hip_runtime.h>

// Modulated deformable depthwise conv, B=8 C=128 H=W=64 K=3 PAD=1 STRIDE=1.
// Round 4: float4 channel-interleaved LDS window (every bilinear corner =
// ONE ds_read_b128 serving 4 channels) + REGISTER staging (round-2/3's
// global_load_lds scatter amplified L2-miss traffic 7x; reg staging is
// coalesced and lets pads be zeroed in-register -> unmasked weights).
// Double-buffered, loads prefetched before compute. XCD-chunked block
// remap groups the 8 hs-sibling blocks (shared window rows) per XCD L2.

#define BB 8
#define CC 128
#define HH 64
#define WW 64
#define HWs (HH*WW)
#define KKT 9
#define CH 8               // channels per block
#define NCG (CC/CH)        // 16
#define CPI 4              // channels interleaved per LDS buffer
#define NIT (CH/CPI)       // 2
#define ROWS 8
#define NHS (HH/ROWS)      // 8
#define WLO 6
#define WR  22
#define CLO 6
#define WC  76
#define CELLS (WR*WC)      // 1672 float4 cells (53.5 KB both buffers)
#define NTHR 512
#define NK  ((CELLS + NTHR - 1)/NTHR)   // 4

__global__ __launch_bounds__(NTHR, 6)
void mdcn_kernel(const float* __restrict__ x,
                 const float* __restrict__ offset,
                 const float* __restrict__ mask,
                 const float* __restrict__ dynw,
                 float* __restrict__ out)
{
    __shared__ float4 lds[2][CELLS];

    // bijective XCD-chunked remap: dispatcher assigns xcd = physical%8;
    // logical-contiguous blocks (hs siblings sharing window rows) land
    // on the same XCD's L2. 1024 = 8 XCD * 128.
    const int pb  = blockIdx.x;
    const int blk = (pb & 7) * 128 + (pb >> 3);
    const int hs = blk & (NHS - 1);
    const int cg = (blk >> 3) & (NCG - 1);
    const int b  = blk >> 7;
    const int tid = threadIdx.x;
    const int w = tid & 63;
    const int h0 = hs * ROWS;
    const int h = h0 + (tid >> 6);

    const float* xg = x + (size_t)(b * CC + cg * CH) * HWs;

    // ---- register staging: 4 coalesced streams (one per channel plane),
    // pads zeroed in-register ----
    float4 stg[NK];
    #define STAGE_LOAD(XP)                                                    \
    do {                                                                      \
        const float* xp_ = (XP);                                              \
        _Pragma("unroll")                                                     \
        for (int k = 0; k < NK; ++k) {                                        \
            const int idx = tid + k * NTHR;                                   \
            float4 v = make_float4(0.f, 0.f, 0.f, 0.f);                       \
            if (idx < CELLS) {                                                \
                const int row = idx / WC;                                     \
                const int col = idx - row * WC - CLO;                         \
                const int ar  = h0 - WLO + row;                               \
                if ((unsigned)ar < (unsigned)HH &&                            \
                    (unsigned)col < (unsigned)WW) {                           \
                    const float* pp = xp_ + ar * WW + col;                    \
                    v.x = pp[0 * HWs]; v.y = pp[1 * HWs];                     \
                    v.z = pp[2 * HWs]; v.w = pp[3 * HWs];                     \
                }                                                             \
            }                                                                 \
            stg[k] = v;                                                       \
        }                                                                     \
    } while (0)

    #define STAGE_WRITE(DST)                                                  \
    do {                                                                      \
        float4* Lb_ = &lds[DST][0];                                           \
        _Pragma("unroll")                                                     \
        for (int k = 0; k < NK; ++k) {                                        \
            const int idx = tid + k * NTHR;                                   \
            if (idx < CELLS) Lb_[idx] = stg[k];                               \
        }                                                                     \
    } while (0)

    // prologue: issue group-0 loads, overlap metadata, then write buf0
    STAGE_LOAD(xg);

    // ---- per-tap metadata (channel-invariant, fully static-indexed) ----
    float fw[KKT][4];
    int   woff[KKT];
    int   badmask = 0;
    const float* offp = offset + (size_t)b * (2 * KKT) * HWs + h * WW + w;
    const float* mskp = mask   + (size_t)b * KKT * HWs       + h * WW + w;
    #pragma unroll
    for (int t = 0; t < KKT; ++t) {
        const float oy = offp[(2 * t)     * HWs];
        const float ox = offp[(2 * t + 1) * HWs];
        const float m  = mskp[t * HWs];
        const float py = (float)(h - 1 + t / 3) + oy;
        const float px = (float)(w - 1 + t % 3) + ox;
        const float fy = floorf(py), fx = floorf(px);
        const float dy = py - fy,    dx = px - fx;
        const int y0 = (int)fy, x0 = (int)fx;
        const bool inwin = (y0 >= h0 - WLO) && (y0 <= h0 - WLO + WR - 2) &&
                           (x0 >= -CLO)     && (x0 <= -CLO + WC - 2);
        if (!inwin) {
            badmask |= (1 << t);
            woff[t] = 0;
            fw[t][0] = fw[t][1] = fw[t][2] = fw[t][3] = 0.f;
        } else {
            woff[t] = (y0 - (h0 - WLO)) * WC + (x0 + CLO);
            const float omdy = 1.f - dy, omdx = 1.f - dx;
            fw[t][0] = omdy * omdx * m;   // pads hold zeros -> no masking
            fw[t][1] = omdy * dx   * m;
            fw[t][2] = dy   * omdx * m;
            fw[t][3] = dy   * dx   * m;
        }
    }
    const int anybad = __any(badmask != 0);

    STAGE_WRITE(0);
    __syncthreads();

    const float* wtb  = dynw + (size_t)(b * CC + cg * CH) * KKT;
    float*       outp = out  + (size_t)(b * CC + cg * CH) * HWs + h * WW + w;

    for (int it = 0; it < NIT; ++it) {
        // prefetch next group's global loads (hide HBM/L2 latency under compute)
        if (it + 1 < NIT) {
            STAGE_LOAD(xg + (size_t)(it + 1) * CPI * HWs);
        }

        const float4* Lp = &lds[it & 1][0];
        const float*  wt = wtb + it * CPI * KKT;
        float s0 = 0.f, s1 = 0.f, s2 = 0.f, s3 = 0.f;

        #pragma unroll
        for (int t = 0; t < KKT; ++t) {
            const float4 c00 = Lp[woff[t]];
            const float4 c01 = Lp[woff[t] + 1];
            const float4 c10 = Lp[woff[t] + WC];
            const float4 c11 = Lp[woff[t] + WC + 1];
            const float w00 = fw[t][0], w01 = fw[t][1];
            const float w10 = fw[t][2], w11 = fw[t][3];
            const float v0 = c00.x * w00 + c01.x * w01 + c10.x * w10 + c11.x * w11;
            const float v1 = c00.y * w00 + c01.y * w01 + c10.y * w10 + c11.y * w11;
            const float v2 = c00.z * w00 + c01.z * w01 + c10.z * w10 + c11.z * w11;
            const float v3 = c00.w * w00 + c01.w * w01 + c10.w * w10 + c11.w * w11;
            s0 += v0 * wt[0 * KKT + t];
            s1 += v1 * wt[1 * KKT + t];
            s2 += v2 * wt[2 * KKT + t];
            s3 += v3 * wt[3 * KKT + t];
        }

        // rare corrective path for out-of-window taps (exact reference math)
        if (anybad) {
            #pragma unroll
            for (int t = 0; t < KKT; ++t) {
                if (badmask & (1 << t)) {
                    const float oy = offp[(2 * t)     * HWs];
                    const float ox = offp[(2 * t + 1) * HWs];
                    const float m  = mskp[t * HWs];
                    const float py = (float)(h - 1 + t / 3) + oy;
                    const float px = (float)(w - 1 + t % 3) + ox;
                    const float fy = floorf(py), fx = floorf(px);
                    const float dy = py - fy, dx = px - fx;
                    const int y0 = (int)fy, x0 = (int)fx;
                    const int y1 = y0 + 1,  x1 = x0 + 1;
                    const int cy0 = min(max(y0, 0), HH - 1);
                    const int cy1 = min(max(y1, 0), HH - 1);
                    const int cx0 = min(max(x0, 0), WW - 1);
                    const int cx1 = min(max(x1, 0), WW - 1);
                    const float m00 = ((unsigned)y0 < HH && (unsigned)x0 < WW) ? 1.f : 0.f;
                    const float m01 = ((unsigned)y0 < HH && (unsigned)x1 < WW) ? 1.f : 0.f;
                    const float m10 = ((unsigned)y1 < HH && (unsigned)x0 < WW) ? 1.f : 0.f;
                    const float m11 = ((unsigned)y1 < HH && (unsigned)x1 < WW) ? 1.f : 0.f;
                    const float omdy = 1.f - dy, omdx = 1.f - dx;
                    #pragma unroll
                    for (int c = 0; c < CPI; ++c) {
                        const float* pl = xg + (size_t)(it * CPI + c) * HWs;
                        const float v = pl[cy0 * WW + cx0] * m00 * (omdy * omdx)
                                      + pl[cy0 * WW + cx1] * m01 * (omdy * dx)
                                      + pl[cy1 * WW + cx0] * m10 * (dy * omdx)
                                      + pl[cy1 * WW + cx1] * m11 * (dy * dx);
                        const float add = v * m * wt[c * KKT + t];
                        if      (c == 0) s0 += add;
                        else if (c == 1) s1 += add;
                        else if (c == 2) s2 += add;
                        else             s3 += add;
                    }
                }
            }
        }

        outp[(size_t)(it * CPI + 0) * HWs] = s0;
        outp[(size_t)(it * CPI + 1) * HWs] = s1;
        outp[(size_t)(it * CPI + 2) * HWs] = s2;
        outp[(size_t)(it * CPI + 3) * HWs] = s3;

        if (it + 1 < NIT) {
            STAGE_WRITE((it + 1) & 1);
            __syncthreads();
        }
    }
    #undef STAGE_LOAD
    #undef STAGE_WRITE
}

extern "C" void kernel_launch(void* const* d_in, const int* in_sizes, int n_in,
                              void* d_out, int out_size, void* d_ws, size_t ws_size,
                              hipStream_t stream) {
    const float* x      = (const float*)d_in[0];
    const float* offset = (const float*)d_in[1];
    const float* mask   = (const float*)d_in[2];
    const float* dynw   = (const float*)d_in[3];
    float* out = (float*)d_out;

    dim3 grid(BB * NCG * NHS);   // 1024 blocks
    dim3 block(NTHR);
    mdcn_kernel<<<grid, block, 0, stream>>>(x, offset, mask, dynw, out);
}

// Round 6
// 68.187 us; speedup vs baseline: 2.1977x; 2.1977x over previous
//
#include <hip/hip_runtime.h>

// Modulated deformable depthwise conv, B=8 C=128 H=W=64 K=3 PAD=1 STRIDE=1.
// Round 5: round-4 structure with the spill bug fixed. Root cause of
// rounds 3/4 slowness: __launch_bounds__(512,6) capped VGPRs at ~40 ->
// per-thread tap metadata spilled to scratch (WRITE_SIZE 460MB vs 16MB
// output). Fix: __launch_bounds__(512,4) (128-reg cap), compact tap
// state to (m,dy,dx) per tap (27 regs) with corner weights recomputed
// in-loop, natural block order (round-1 evidence: 27MB FETCH).

#define BB 8
#define CC 128
#define HH 64
#define WW 64
#define HWs (HH*WW)
#define KKT 9
#define CH 8               // channels per block
#define NCG (CC/CH)        // 16
#define CPI 4              // channels interleaved per LDS float4 cell
#define NIT (CH/CPI)       // 2
#define ROWS 8
#define NHS (HH/ROWS)      // 8
#define WLO 6
#define WR  22
#define CLO 6
#define WC  76
#define CELLS (WR*WC)      // 1672 float4 cells; 26.75 KB/buffer
#define NTHR 512
#define NK  ((CELLS + NTHR - 1)/NTHR)   // 4

__global__ __launch_bounds__(NTHR, 4)
void mdcn_kernel(const float* __restrict__ x,
                 const float* __restrict__ offset,
                 const float* __restrict__ mask,
                 const float* __restrict__ dynw,
                 float* __restrict__ out)
{
    __shared__ float4 lds[2][CELLS];

    const int blk = blockIdx.x;
    const int hs = blk & (NHS - 1);
    const int cg = (blk >> 3) & (NCG - 1);
    const int b  = blk >> 7;
    const int tid = threadIdx.x;
    const int w = tid & 63;
    const int h0 = hs * ROWS;
    const int h = h0 + (tid >> 6);

    const float* xg = x + (size_t)(b * CC + cg * CH) * HWs;

    // ---- register staging: 4 coalesced per-plane streams, pads zeroed ----
    float4 stg[NK];
    #define STAGE_LOAD(XP)                                                    \
    do {                                                                      \
        const float* xp_ = (XP);                                              \
        _Pragma("unroll")                                                     \
        for (int k = 0; k < NK; ++k) {                                        \
            const int idx = tid + k * NTHR;                                   \
            float4 v = make_float4(0.f, 0.f, 0.f, 0.f);                       \
            if (idx < CELLS) {                                                \
                const int row = idx / WC;                                     \
                const int col = idx - row * WC - CLO;                         \
                const int ar  = h0 - WLO + row;                               \
                if ((unsigned)ar < (unsigned)HH &&                            \
                    (unsigned)col < (unsigned)WW) {                           \
                    const float* pp = xp_ + ar * WW + col;                    \
                    v.x = pp[0 * HWs]; v.y = pp[1 * HWs];                     \
                    v.z = pp[2 * HWs]; v.w = pp[3 * HWs];                     \
                }                                                             \
            }                                                                 \
            stg[k] = v;                                                       \
        }                                                                     \
    } while (0)

    #define STAGE_WRITE(DST)                                                  \
    do {                                                                      \
        float4* Lb_ = &lds[DST][0];                                           \
        _Pragma("unroll")                                                     \
        for (int k = 0; k < NK; ++k) {                                        \
            const int idx = tid + k * NTHR;                                   \
            if (idx < CELLS) Lb_[idx] = stg[k];                               \
        }                                                                     \
    } while (0)

    // prologue: issue group-0 loads; metadata overlaps load latency
    STAGE_LOAD(xg);

    // ---- per-tap metadata: m, dy, dx + window offset (compact) ----
    float mv[KKT], dyv[KKT], dxv[KKT];
    int   woff[KKT];
    int   badmask = 0;
    const float* offp = offset + (size_t)b * (2 * KKT) * HWs + h * WW + w;
    const float* mskp = mask   + (size_t)b * KKT * HWs       + h * WW + w;
    #pragma unroll
    for (int t = 0; t < KKT; ++t) {
        const float oy = offp[(2 * t)     * HWs];
        const float ox = offp[(2 * t + 1) * HWs];
        const float m  = mskp[t * HWs];
        const float py = (float)(h - 1 + t / 3) + oy;
        const float px = (float)(w - 1 + t % 3) + ox;
        const float fy = floorf(py), fx = floorf(px);
        const int y0 = (int)fy, x0 = (int)fx;
        dyv[t] = py - fy;
        dxv[t] = px - fx;
        const bool inwin = (y0 >= h0 - WLO) && (y0 <= h0 - WLO + WR - 2) &&
                           (x0 >= -CLO)     && (x0 <= -CLO + WC - 2);
        if (!inwin) {
            badmask |= (1 << t);
            woff[t] = 0;
            mv[t] = 0.f;               // kills the LDS contribution
        } else {
            woff[t] = (y0 - (h0 - WLO)) * WC + (x0 + CLO);
            mv[t] = m;                 // pads hold zeros -> no corner masks
        }
    }
    const int anybad = __any(badmask != 0);

    STAGE_WRITE(0);
    __syncthreads();

    const float* wtb  = dynw + (size_t)(b * CC + cg * CH) * KKT;
    float*       outp = out  + (size_t)(b * CC + cg * CH) * HWs + h * WW + w;

    for (int it = 0; it < NIT; ++it) {
        if (it + 1 < NIT) {
            STAGE_LOAD(xg + (size_t)(it + 1) * CPI * HWs);   // prefetch
        }

        const float4* Lp = &lds[it & 1][0];
        const float*  wt = wtb + it * CPI * KKT;
        float s0 = 0.f, s1 = 0.f, s2 = 0.f, s3 = 0.f;

        #pragma unroll
        for (int t = 0; t < KKT; ++t) {
            const float4 c00 = Lp[woff[t]];
            const float4 c01 = Lp[woff[t] + 1];
            const float4 c10 = Lp[woff[t] + WC];
            const float4 c11 = Lp[woff[t] + WC + 1];
            const float dy = dyv[t], dx = dxv[t], m = mv[t];
            const float omdy = 1.f - dy, omdx = 1.f - dx;
            const float w00 = omdy * omdx * m, w01 = omdy * dx * m;
            const float w10 = dy * omdx * m,   w11 = dy * dx * m;
            const float v0 = c00.x * w00 + c01.x * w01 + c10.x * w10 + c11.x * w11;
            const float v1 = c00.y * w00 + c01.y * w01 + c10.y * w10 + c11.y * w11;
            const float v2 = c00.z * w00 + c01.z * w01 + c10.z * w10 + c11.z * w11;
            const float v3 = c00.w * w00 + c01.w * w01 + c10.w * w10 + c11.w * w11;
            s0 += v0 * wt[0 * KKT + t];
            s1 += v1 * wt[1 * KKT + t];
            s2 += v2 * wt[2 * KKT + t];
            s3 += v3 * wt[3 * KKT + t];
        }

        // rare corrective path for out-of-window taps (exact reference math)
        if (anybad) {
            #pragma unroll
            for (int t = 0; t < KKT; ++t) {
                if (badmask & (1 << t)) {
                    const float oy = offp[(2 * t)     * HWs];
                    const float ox = offp[(2 * t + 1) * HWs];
                    const float m  = mskp[t * HWs];
                    const float py = (float)(h - 1 + t / 3) + oy;
                    const float px = (float)(w - 1 + t % 3) + ox;
                    const float fy = floorf(py), fx = floorf(px);
                    const float dy = py - fy, dx = px - fx;
                    const int y0 = (int)fy, x0 = (int)fx;
                    const int y1 = y0 + 1,  x1 = x0 + 1;
                    const int cy0 = min(max(y0, 0), HH - 1);
                    const int cy1 = min(max(y1, 0), HH - 1);
                    const int cx0 = min(max(x0, 0), WW - 1);
                    const int cx1 = min(max(x1, 0), WW - 1);
                    const float m00 = ((unsigned)y0 < HH && (unsigned)x0 < WW) ? 1.f : 0.f;
                    const float m01 = ((unsigned)y0 < HH && (unsigned)x1 < WW) ? 1.f : 0.f;
                    const float m10 = ((unsigned)y1 < HH && (unsigned)x0 < WW) ? 1.f : 0.f;
                    const float m11 = ((unsigned)y1 < HH && (unsigned)x1 < WW) ? 1.f : 0.f;
                    const float omdy = 1.f - dy, omdx = 1.f - dx;
                    #pragma unroll
                    for (int c = 0; c < CPI; ++c) {
                        const float* pl = xg + (size_t)(it * CPI + c) * HWs;
                        const float v = pl[cy0 * WW + cx0] * m00 * (omdy * omdx)
                                      + pl[cy0 * WW + cx1] * m01 * (omdy * dx)
                                      + pl[cy1 * WW + cx0] * m10 * (dy * omdx)
                                      + pl[cy1 * WW + cx1] * m11 * (dy * dx);
                        const float add = v * m * wt[c * KKT + t];
                        if      (c == 0) s0 += add;
                        else if (c == 1) s1 += add;
                        else if (c == 2) s2 += add;
                        else             s3 += add;
                    }
                }
            }
        }

        outp[(size_t)(it * CPI + 0) * HWs] = s0;
        outp[(size_t)(it * CPI + 1) * HWs] = s1;
        outp[(size_t)(it * CPI + 2) * HWs] = s2;
        outp[(size_t)(it * CPI + 3) * HWs] = s3;

        if (it + 1 < NIT) {
            STAGE_WRITE((it + 1) & 1);
            __syncthreads();
        }
    }
    #undef STAGE_LOAD
    #undef STAGE_WRITE
}

extern "C" void kernel_launch(void* const* d_in, const int* in_sizes, int n_in,
                              void* d_out, int out_size, void* d_ws, size_t ws_size,
                              hipStream_t stream) {
    const float* x      = (const float*)d_in[0];
    const float* offset = (const float*)d_in[1];
    const float* mask   = (const float*)d_in[2];
    const float* dynw   = (const float*)d_in[3];
    float* out = (float*)d_out;

    dim3 grid(BB * NCG * NHS);   // 1024 blocks
    dim3 block(NTHR);
    mdcn_kernel<<<grid, block, 0, stream>>>(x, offset, mask, dynw, out);
}

// Round 7
// 41.284 us; speedup vs baseline: 3.6298x; 1.6517x over previous
//
#include <hip/hip_runtime.h>

// Modulated deformable depthwise conv, B=8 C=128 H=W=64 K=3 PAD=1 STRIDE=1.
// Round 6: round-5 kernel, launch-bounds fix only. Calibrated from our own
// data points ((512,6)->40 VGPR, (512,4)->64 VGPR): hipcc treats the 2nd
// __launch_bounds__ arg as min BLOCKS per CU (CUDA semantics). LDS (53.76
// KB/block) already caps residency at 2 blocks/CU, so (512,2) -> 128-VGPR
// cap -> no scratch spill (round 5: 208 MB/dispatch of scratch writes).

#define BB 8
#define CC 128
#define HH 64
#define WW 64
#define HWs (HH*WW)
#define KKT 9
#define CH 8               // channels per block
#define NCG (CC/CH)        // 16
#define CPI 4              // channels interleaved per LDS float4 cell
#define NIT (CH/CPI)       // 2
#define ROWS 8
#define NHS (HH/ROWS)      // 8
#define WLO 6
#define WR  22
#define CLO 6
#define WC  76
#define CELLS (WR*WC)      // 1672 float4 cells; 26.75 KB/buffer
#define NTHR 512
#define NK  ((CELLS + NTHR - 1)/NTHR)   // 4

__global__ __launch_bounds__(NTHR, 2)
void mdcn_kernel(const float* __restrict__ x,
                 const float* __restrict__ offset,
                 const float* __restrict__ mask,
                 const float* __restrict__ dynw,
                 float* __restrict__ out)
{
    __shared__ float4 lds[2][CELLS];

    const int blk = blockIdx.x;
    const int hs = blk & (NHS - 1);
    const int cg = (blk >> 3) & (NCG - 1);
    const int b  = blk >> 7;
    const int tid = threadIdx.x;
    const int w = tid & 63;
    const int h0 = hs * ROWS;
    const int h = h0 + (tid >> 6);

    const float* xg = x + (size_t)(b * CC + cg * CH) * HWs;

    // ---- register staging: 4 coalesced per-plane streams, pads zeroed ----
    float4 stg[NK];
    #define STAGE_LOAD(XP)                                                    \
    do {                                                                      \
        const float* xp_ = (XP);                                              \
        _Pragma("unroll")                                                     \
        for (int k = 0; k < NK; ++k) {                                        \
            const int idx = tid + k * NTHR;                                   \
            float4 v = make_float4(0.f, 0.f, 0.f, 0.f);                       \
            if (idx < CELLS) {                                                \
                const int row = idx / WC;                                     \
                const int col = idx - row * WC - CLO;                         \
                const int ar  = h0 - WLO + row;                               \
                if ((unsigned)ar < (unsigned)HH &&                            \
                    (unsigned)col < (unsigned)WW) {                           \
                    const float* pp = xp_ + ar * WW + col;                    \
                    v.x = pp[0 * HWs]; v.y = pp[1 * HWs];                     \
                    v.z = pp[2 * HWs]; v.w = pp[3 * HWs];                     \
                }                                                             \
            }                                                                 \
            stg[k] = v;                                                       \
        }                                                                     \
    } while (0)

    #define STAGE_WRITE(DST)                                                  \
    do {                                                                      \
        float4* Lb_ = &lds[DST][0];                                           \
        _Pragma("unroll")                                                     \
        for (int k = 0; k < NK; ++k) {                                        \
            const int idx = tid + k * NTHR;                                   \
            if (idx < CELLS) Lb_[idx] = stg[k];                               \
        }                                                                     \
    } while (0)

    // prologue: issue group-0 loads; metadata overlaps load latency
    STAGE_LOAD(xg);

    // ---- per-tap metadata: m, dy, dx + window offset (compact) ----
    float mv[KKT], dyv[KKT], dxv[KKT];
    int   woff[KKT];
    int   badmask = 0;
    const float* offp = offset + (size_t)b * (2 * KKT) * HWs + h * WW + w;
    const float* mskp = mask   + (size_t)b * KKT * HWs       + h * WW + w;
    #pragma unroll
    for (int t = 0; t < KKT; ++t) {
        const float oy = offp[(2 * t)     * HWs];
        const float ox = offp[(2 * t + 1) * HWs];
        const float m  = mskp[t * HWs];
        const float py = (float)(h - 1 + t / 3) + oy;
        const float px = (float)(w - 1 + t % 3) + ox;
        const float fy = floorf(py), fx = floorf(px);
        const int y0 = (int)fy, x0 = (int)fx;
        dyv[t] = py - fy;
        dxv[t] = px - fx;
        const bool inwin = (y0 >= h0 - WLO) && (y0 <= h0 - WLO + WR - 2) &&
                           (x0 >= -CLO)     && (x0 <= -CLO + WC - 2);
        if (!inwin) {
            badmask |= (1 << t);
            woff[t] = 0;
            mv[t] = 0.f;               // kills the LDS contribution
        } else {
            woff[t] = (y0 - (h0 - WLO)) * WC + (x0 + CLO);
            mv[t] = m;                 // pads hold zeros -> no corner masks
        }
    }
    const int anybad = __any(badmask != 0);

    STAGE_WRITE(0);
    __syncthreads();

    const float* wtb  = dynw + (size_t)(b * CC + cg * CH) * KKT;
    float*       outp = out  + (size_t)(b * CC + cg * CH) * HWs + h * WW + w;

    for (int it = 0; it < NIT; ++it) {
        if (it + 1 < NIT) {
            STAGE_LOAD(xg + (size_t)(it + 1) * CPI * HWs);   // prefetch
        }

        const float4* Lp = &lds[it & 1][0];
        const float*  wt = wtb + it * CPI * KKT;
        float s0 = 0.f, s1 = 0.f, s2 = 0.f, s3 = 0.f;

        #pragma unroll
        for (int t = 0; t < KKT; ++t) {
            const float4 c00 = Lp[woff[t]];
            const float4 c01 = Lp[woff[t] + 1];
            const float4 c10 = Lp[woff[t] + WC];
            const float4 c11 = Lp[woff[t] + WC + 1];
            const float dy = dyv[t], dx = dxv[t], m = mv[t];
            const float omdy = 1.f - dy, omdx = 1.f - dx;
            const float w00 = omdy * omdx * m, w01 = omdy * dx * m;
            const float w10 = dy * omdx * m,   w11 = dy * dx * m;
            const float v0 = c00.x * w00 + c01.x * w01 + c10.x * w10 + c11.x * w11;
            const float v1 = c00.y * w00 + c01.y * w01 + c10.y * w10 + c11.y * w11;
            const float v2 = c00.z * w00 + c01.z * w01 + c10.z * w10 + c11.z * w11;
            const float v3 = c00.w * w00 + c01.w * w01 + c10.w * w10 + c11.w * w11;
            s0 += v0 * wt[0 * KKT + t];
            s1 += v1 * wt[1 * KKT + t];
            s2 += v2 * wt[2 * KKT + t];
            s3 += v3 * wt[3 * KKT + t];
        }

        // rare corrective path for out-of-window taps (exact reference math)
        if (anybad) {
            #pragma unroll
            for (int t = 0; t < KKT; ++t) {
                if (badmask & (1 << t)) {
                    const float oy = offp[(2 * t)     * HWs];
                    const float ox = offp[(2 * t + 1) * HWs];
                    const float m  = mskp[t * HWs];
                    const float py = (float)(h - 1 + t / 3) + oy;
                    const float px = (float)(w - 1 + t % 3) + ox;
                    const float fy = floorf(py), fx = floorf(px);
                    const float dy = py - fy, dx = px - fx;
                    const int y0 = (int)fy, x0 = (int)fx;
                    const int y1 = y0 + 1,  x1 = x0 + 1;
                    const int cy0 = min(max(y0, 0), HH - 1);
                    const int cy1 = min(max(y1, 0), HH - 1);
                    const int cx0 = min(max(x0, 0), WW - 1);
                    const int cx1 = min(max(x1, 0), WW - 1);
                    const float m00 = ((unsigned)y0 < HH && (unsigned)x0 < WW) ? 1.f : 0.f;
                    const float m01 = ((unsigned)y0 < HH && (unsigned)x1 < WW) ? 1.f : 0.f;
                    const float m10 = ((unsigned)y1 < HH && (unsigned)x0 < WW) ? 1.f : 0.f;
                    const float m11 = ((unsigned)y1 < HH && (unsigned)x1 < WW) ? 1.f : 0.f;
                    const float omdy = 1.f - dy, omdx = 1.f - dx;
                    #pragma unroll
                    for (int c = 0; c < CPI; ++c) {
                        const float* pl = xg + (size_t)(it * CPI + c) * HWs;
                        const float v = pl[cy0 * WW + cx0] * m00 * (omdy * omdx)
                                      + pl[cy0 * WW + cx1] * m01 * (omdy * dx)
                                      + pl[cy1 * WW + cx0] * m10 * (dy * omdx)
                                      + pl[cy1 * WW + cx1] * m11 * (dy * dx);
                        const float add = v * m * wt[c * KKT + t];
                        if      (c == 0) s0 += add;
                        else if (c == 1) s1 += add;
                        else if (c == 2) s2 += add;
                        else             s3 += add;
                    }
                }
            }
        }

        outp[(size_t)(it * CPI + 0) * HWs] = s0;
        outp[(size_t)(it * CPI + 1) * HWs] = s1;
        outp[(size_t)(it * CPI + 2) * HWs] = s2;
        outp[(size_t)(it * CPI + 3) * HWs] = s3;

        if (it + 1 < NIT) {
            STAGE_WRITE((it + 1) & 1);
            __syncthreads();
        }
    }
    #undef STAGE_LOAD
    #undef STAGE_WRITE
}

extern "C" void kernel_launch(void* const* d_in, const int* in_sizes, int n_in,
                              void* d_out, int out_size, void* d_ws, size_t ws_size,
                              hipStream_t stream) {
    const float* x      = (const float*)d_in[0];
    const float* offset = (const float*)d_in[1];
    const float* mask   = (const float*)d_in[2];
    const float* dynw   = (const float*)d_in[3];
    float* out = (float*)d_out;

    dim3 grid(BB * NCG * NHS);   // 1024 blocks
    dim3 block(NTHR);
    mdcn_kernel<<<grid, block, 0, stream>>>(x, offset, mask, dynw, out);
}